// Round 1
// baseline (241.071 us; speedup 1.0000x reference)
//
#include <hip/hip_runtime.h>

#define BB 8
#define NN 2048
#define FF 128
#define NL 2
#define SLOPE 0.1f
#define CHUNK 64
#define NCHUNK (NN / CHUNK)   // 32

__device__ __forceinline__ float lrelu(float v) { return v >= 0.f ? v : SLOPE * v; }

// ---------------------------------------------------------------------------
// Kernel A: w1 = lrelu(x@W3+b3), w2 = lrelu(x@W4+b4).  32 rows / block.
// ---------------------------------------------------------------------------
__global__ __launch_bounds__(256) void k_w12(
    const float* __restrict__ x, const float* __restrict__ W3,
    const float* __restrict__ b3, const float* __restrict__ W4,
    const float* __restrict__ b4, float* __restrict__ w1, float* __restrict__ w2)
{
    __shared__ float xs[32 * FF];
    const int tid = threadIdx.x;
    const int row0 = blockIdx.x * 32;

    const float4* xg = (const float4*)(x + (size_t)row0 * FF);
    float4* xs4 = (float4*)xs;
#pragma unroll
    for (int i = 0; i < 4; i++) xs4[i * 256 + tid] = xg[i * 256 + tid];
    __syncthreads();

    const int col = tid & 127;
    const int rh = tid >> 7;

    float acc1[16], acc2[16];
#pragma unroll
    for (int r = 0; r < 16; r++) { acc1[r] = 0.f; acc2[r] = 0.f; }

    for (int k4 = 0; k4 < FF / 4; k4++) {
        float w3v[4], w4v[4];
#pragma unroll
        for (int j = 0; j < 4; j++) {
            w3v[j] = W3[(k4 * 4 + j) * FF + col];
            w4v[j] = W4[(k4 * 4 + j) * FF + col];
        }
#pragma unroll
        for (int r = 0; r < 16; r++) {
            const float4 xv = *(const float4*)&xs[(2 * r + rh) * FF + k4 * 4];
            acc1[r] = fmaf(xv.x, w3v[0], acc1[r]);
            acc1[r] = fmaf(xv.y, w3v[1], acc1[r]);
            acc1[r] = fmaf(xv.z, w3v[2], acc1[r]);
            acc1[r] = fmaf(xv.w, w3v[3], acc1[r]);
            acc2[r] = fmaf(xv.x, w4v[0], acc2[r]);
            acc2[r] = fmaf(xv.y, w4v[1], acc2[r]);
            acc2[r] = fmaf(xv.z, w4v[2], acc2[r]);
            acc2[r] = fmaf(xv.w, w4v[3], acc2[r]);
        }
    }

    const float bv3 = b3[col], bv4 = b4[col];
#pragma unroll
    for (int r = 0; r < 16; r++) {
        const int row = row0 + 2 * r + rh;
        w1[(size_t)row * FF + col] = lrelu(acc1[r] + bv3);
        w2[(size_t)row * FF + col] = lrelu(acc2[r] + bv4);
    }
}

// ---------------------------------------------------------------------------
// Kernel B: partial S for a 64-row chunk: Spart[chunk][f][g] = sum_j w2[j][f]*x[j][g]
// ---------------------------------------------------------------------------
__global__ __launch_bounds__(256) void k_spart(
    const float* __restrict__ x, const float* __restrict__ w2,
    float* __restrict__ Spart)
{
    __shared__ float w2s[CHUNK * FF];
    __shared__ float xs[CHUNK * FF];
    const int tid = threadIdx.x;
    const int b = blockIdx.x / NCHUNK;
    const int c = blockIdx.x % NCHUNK;
    const size_t base = ((size_t)b * NN + (size_t)c * CHUNK) * FF;

    const float4* w2g = (const float4*)(w2 + base);
    const float4* xg = (const float4*)(x + base);
    float4* a4 = (float4*)w2s;
    float4* c4 = (float4*)xs;
#pragma unroll
    for (int i = 0; i < 8; i++) {
        a4[i * 256 + tid] = w2g[i * 256 + tid];
        c4[i * 256 + tid] = xg[i * 256 + tid];
    }
    __syncthreads();

    const int f0 = (tid >> 4) * 8;
    const int g0 = (tid & 15) * 8;
    float acc[8][8];
#pragma unroll
    for (int i = 0; i < 8; i++)
#pragma unroll
        for (int g = 0; g < 8; g++) acc[i][g] = 0.f;

    for (int j = 0; j < CHUNK; j++) {
        float wv[8], xv[8];
        *(float4*)&wv[0] = *(const float4*)&w2s[j * FF + f0];
        *(float4*)&wv[4] = *(const float4*)&w2s[j * FF + f0 + 4];
        *(float4*)&xv[0] = *(const float4*)&xs[j * FF + g0];
        *(float4*)&xv[4] = *(const float4*)&xs[j * FF + g0 + 4];
#pragma unroll
        for (int i = 0; i < 8; i++)
#pragma unroll
            for (int g = 0; g < 8; g++)
                acc[i][g] = fmaf(wv[i], xv[g], acc[i][g]);
    }

    float* outp = Spart + (size_t)blockIdx.x * FF * FF;
#pragma unroll
    for (int i = 0; i < 8; i++) {
#pragma unroll
        for (int g4 = 0; g4 < 2; g4++) {
            float4 v = make_float4(acc[i][g4 * 4], acc[i][g4 * 4 + 1],
                                   acc[i][g4 * 4 + 2], acc[i][g4 * 4 + 3]);
            *(float4*)&outp[(f0 + i) * FF + g0 + g4 * 4] = v;
        }
    }
}

// ---------------------------------------------------------------------------
// Kernel R: S[b][fg] = sum_c Spart[b*NCHUNK+c][fg]
// ---------------------------------------------------------------------------
__global__ __launch_bounds__(256) void k_sreduce(
    const float* __restrict__ Spart, float* __restrict__ S)
{
    const int idx = blockIdx.x * 256 + threadIdx.x;   // over BB*FF*FF = 131072
    const int b = idx >> 14;
    const int fg = idx & 16383;
    const float* p = Spart + ((size_t)b * NCHUNK) * (FF * FF) + fg;
    float s = 0.f;
#pragma unroll
    for (int c = 0; c < NCHUNK; c++) s += p[(size_t)c * FF * FF];
    S[idx] = s;
}

// ---------------------------------------------------------------------------
// Kernel C1: msg = (w1 @ S_b - diag * x) / (N-1), diag computed inline.
// ---------------------------------------------------------------------------
__global__ __launch_bounds__(256) void k_msg(
    const float* __restrict__ x, const float* __restrict__ w1,
    const float* __restrict__ w2, const float* __restrict__ S,
    float* __restrict__ msg)
{
    __shared__ float w1s[32 * FF];
    __shared__ float diagp[32][8];
    __shared__ float diags[32];
    const int tid = threadIdx.x;
    const int row0 = blockIdx.x * 32;
    const int b = row0 / NN;
    const float* Sb = S + (size_t)b * FF * FF;

    const float4* w1g = (const float4*)(w1 + (size_t)row0 * FF);
    float4* s4 = (float4*)w1s;
#pragma unroll
    for (int i = 0; i < 4; i++) s4[i * 256 + tid] = w1g[i * 256 + tid];

    {   // diag partials: 8 threads per row, 16 elems each
        const int r = tid >> 3, e0 = (tid & 7) * 16;
        const float* w1r = w1 + (size_t)(row0 + r) * FF + e0;
        const float* w2r = w2 + (size_t)(row0 + r) * FF + e0;
        float p = 0.f;
#pragma unroll
        for (int j = 0; j < 16; j++) p = fmaf(w1r[j], w2r[j], p);
        diagp[r][tid & 7] = p;
    }
    __syncthreads();
    if (tid < 32) {
        float d = 0.f;
#pragma unroll
        for (int j = 0; j < 8; j++) d += diagp[tid][j];
        diags[tid] = d;
    }
    __syncthreads();

    const int col = tid & 127;
    const int rh = tid >> 7;
    float acc[16];
#pragma unroll
    for (int r = 0; r < 16; r++) acc[r] = 0.f;

    for (int k4 = 0; k4 < FF / 4; k4++) {
        float sv[4];
#pragma unroll
        for (int j = 0; j < 4; j++) sv[j] = Sb[(k4 * 4 + j) * FF + col];
#pragma unroll
        for (int r = 0; r < 16; r++) {
            const float4 wv = *(const float4*)&w1s[(2 * r + rh) * FF + k4 * 4];
            acc[r] = fmaf(wv.x, sv[0], acc[r]);
            acc[r] = fmaf(wv.y, sv[1], acc[r]);
            acc[r] = fmaf(wv.z, sv[2], acc[r]);
            acc[r] = fmaf(wv.w, sv[3], acc[r]);
        }
    }

    const float inv = 1.f / (float)(NN - 1);
#pragma unroll
    for (int r = 0; r < 16; r++) {
        const int row = row0 + 2 * r + rh;
        const float xv = x[(size_t)row * FF + col];
        msg[(size_t)row * FF + col] = (acc[r] - diags[2 * r + rh] * xv) * inv;
    }
}

// ---------------------------------------------------------------------------
// Kernel C2: y = lrelu(msg @ W5 + b5) + x   (in-place safe on x==y)
// ---------------------------------------------------------------------------
__global__ __launch_bounds__(256) void k_out(
    const float* __restrict__ xin, const float* __restrict__ msg,
    const float* __restrict__ W5, const float* __restrict__ b5,
    float* __restrict__ y)
{
    __shared__ float ms[32 * FF];
    const int tid = threadIdx.x;
    const int row0 = blockIdx.x * 32;

    const float4* mg = (const float4*)(msg + (size_t)row0 * FF);
    float4* s4 = (float4*)ms;
#pragma unroll
    for (int i = 0; i < 4; i++) s4[i * 256 + tid] = mg[i * 256 + tid];
    __syncthreads();

    const int col = tid & 127;
    const int rh = tid >> 7;
    float acc[16];
#pragma unroll
    for (int r = 0; r < 16; r++) acc[r] = 0.f;

    for (int k4 = 0; k4 < FF / 4; k4++) {
        float wv[4];
#pragma unroll
        for (int j = 0; j < 4; j++) wv[j] = W5[(k4 * 4 + j) * FF + col];
#pragma unroll
        for (int r = 0; r < 16; r++) {
            const float4 mv = *(const float4*)&ms[(2 * r + rh) * FF + k4 * 4];
            acc[r] = fmaf(mv.x, wv[0], acc[r]);
            acc[r] = fmaf(mv.y, wv[1], acc[r]);
            acc[r] = fmaf(mv.z, wv[2], acc[r]);
            acc[r] = fmaf(mv.w, wv[3], acc[r]);
        }
    }

    const float bv = b5[col];
#pragma unroll
    for (int r = 0; r < 16; r++) {
        const int row = row0 + 2 * r + rh;
        const float xv = xin[(size_t)row * FF + col];
        y[(size_t)row * FF + col] = lrelu(acc[r] + bv) + xv;
    }
}

// ---------------------------------------------------------------------------
extern "C" void kernel_launch(void* const* d_in, const int* in_sizes, int n_in,
                              void* d_out, int out_size, void* d_ws, size_t ws_size,
                              hipStream_t stream)
{
    const float* x  = (const float*)d_in[0];
    const float* W3 = (const float*)d_in[1];
    const float* b3 = (const float*)d_in[2];
    const float* W4 = (const float*)d_in[3];
    const float* b4 = (const float*)d_in[4];
    const float* W5 = (const float*)d_in[5];
    const float* b5 = (const float*)d_in[6];
    float* out = (float*)d_out;

    char* ws = (char*)d_ws;
    float* w1    = (float*)(ws);                       // 8 MB
    float* w2    = (float*)(ws + ((size_t)8 << 20));   // 8 MB
    float* msg   = (float*)(ws + ((size_t)16 << 20));  // 8 MB
    float* Spart = (float*)(ws + ((size_t)24 << 20));  // 16 MB (256 x 64KB)
    float* S     = (float*)(ws + ((size_t)40 << 20));  // 512 KB

    const int rowBlocks = BB * NN / 32;   // 512

    for (int l = 0; l < NL; l++) {
        const float* cur = (l == 0) ? x : out;
        const float* W3l = W3 + (size_t)l * FF * FF;
        const float* b3l = b3 + (size_t)l * FF;
        const float* W4l = W4 + (size_t)l * FF * FF;
        const float* b4l = b4 + (size_t)l * FF;
        const float* W5l = W5 + (size_t)l * FF * FF;
        const float* b5l = b5 + (size_t)l * FF;

        k_w12<<<rowBlocks, 256, 0, stream>>>(cur, W3l, b3l, W4l, b4l, w1, w2);
        k_spart<<<BB * NCHUNK, 256, 0, stream>>>(cur, w2, Spart);
        k_sreduce<<<BB * FF * FF / 256, 256, 0, stream>>>(Spart, S);
        k_msg<<<rowBlocks, 256, 0, stream>>>(cur, w1, w2, S, msg);
        k_out<<<rowBlocks, 256, 0, stream>>>(cur, msg, W5l, b5l, out);
    }
}

// Round 2
// 150.484 us; speedup vs baseline: 1.6020x; 1.6020x over previous
//
#include <hip/hip_runtime.h>

#define BB 8
#define NN 2048
#define FF 128
#define NL 2
#define SLOPE 0.1f
#define NROW (BB * NN)          // 16384 total rows
#define XS_STRIDE 136           // padded bf16 row stride in LDS

typedef __attribute__((ext_vector_type(8))) short short8;
typedef __attribute__((ext_vector_type(4))) float f32x4;

__device__ __forceinline__ float lrelu(float v) { return v >= 0.f ? v : SLOPE * v; }

// fp32 -> bf16 round-to-nearest-even
__device__ __forceinline__ ushort f2bf(float f) {
    uint u = __float_as_uint(f);
    return (ushort)((u + 0x7fffu + ((u >> 16) & 1u)) >> 16);
}

// ---------------------------------------------------------------------------
// Prep: transpose all 6 weight matrices to bf16 Wt[m][g][f] = W[m][f][g]
// m = l*3 + {0:W3, 1:W4, 2:W5}
// ---------------------------------------------------------------------------
__global__ __launch_bounds__(256) void k_prep(
    const float* __restrict__ W3, const float* __restrict__ W4,
    const float* __restrict__ W5, ushort* __restrict__ Wt)
{
    const int idx = blockIdx.x * 256 + threadIdx.x;   // 0 .. 98303
    const int m = idx >> 14;
    const int rem = idx & 16383;
    const int f = rem & 127;
    const int g = rem >> 7;
    const int l = m / 3, w = m % 3;
    const float* src = (w == 0) ? W3 : (w == 1) ? W4 : W5;
    Wt[m * 16384 + g * 128 + f] = f2bf(src[l * 16384 + f * 128 + g]);
}

// ---------------------------------------------------------------------------
// K1: w1 = lrelu(x@W3+b3) [bf16 row-major], w2t[b][f][j] = lrelu(x@W4+b4)^T,
//     xt[b][g][j] = x^T (bf16), diag[i] = dot(w1_i, w2_i).  32 rows / block.
// ---------------------------------------------------------------------------
__global__ __launch_bounds__(256) void k_w12(
    const float* __restrict__ x, const ushort* __restrict__ w3t,
    const ushort* __restrict__ w4t, const float* __restrict__ b3,
    const float* __restrict__ b4, ushort* __restrict__ w1b,
    ushort* __restrict__ w2t, ushort* __restrict__ xt,
    float* __restrict__ diag)
{
    __shared__ ushort xs[32 * XS_STRIDE];
    __shared__ float diag_s[32];

    const int tid = threadIdx.x;
    const int row0 = blockIdx.x * 32;
    const int b = row0 >> 11;          // batch
    const int jloc0 = row0 & 2047;     // row within batch

    if (tid < 32) diag_s[tid] = 0.f;

    // stage x tile -> bf16 LDS (row-major, padded)
    const float4* xg4 = (const float4*)(x + (size_t)row0 * FF);
#pragma unroll
    for (int i = 0; i < 4; i++) {
        const int f4 = i * 256 + tid;          // float4 index in tile
        const int row = f4 >> 5;
        const int k = (f4 & 31) * 4;
        float4 v = xg4[f4];
        ushort4 h;
        h.x = f2bf(v.x); h.y = f2bf(v.y); h.z = f2bf(v.z); h.w = f2bf(v.w);
        *(ushort4*)&xs[row * XS_STRIDE + k] = h;
    }
    __syncthreads();

    // write xt[b][g][jloc0..+32] from LDS (transposed read)
    {
        const int g = tid >> 1;
        const int h = tid & 1;
        uint p[8];
#pragma unroll
        for (int jj = 0; jj < 8; jj++) {
            const uint lo = xs[(h * 16 + jj * 2) * XS_STRIDE + g];
            const uint hi = xs[(h * 16 + jj * 2 + 1) * XS_STRIDE + g];
            p[jj] = lo | (hi << 16);
        }
        uint4* dst = (uint4*)&xt[(size_t)b * (FF * NN) + (size_t)g * NN + jloc0 + h * 16];
        dst[0] = make_uint4(p[0], p[1], p[2], p[3]);
        dst[1] = make_uint4(p[4], p[5], p[6], p[7]);
    }

    const int lane = tid & 63;
    const int wave = tid >> 6;
    const int c = lane & 15;
    const int quad = lane >> 4;
    const int ct0 = wave * 2;

    f32x4 acc1[2][2], acc2[2][2];
#pragma unroll
    for (int rt = 0; rt < 2; rt++)
#pragma unroll
        for (int ct = 0; ct < 2; ct++) { acc1[rt][ct] = (f32x4)0.f; acc2[rt][ct] = (f32x4)0.f; }

#pragma unroll
    for (int kk = 0; kk < 4; kk++) {
        short8 a0 = *(const short8*)&xs[c * XS_STRIDE + kk * 32 + quad * 8];
        short8 a1 = *(const short8*)&xs[(16 + c) * XS_STRIDE + kk * 32 + quad * 8];
#pragma unroll
        for (int ct = 0; ct < 2; ct++) {
            const int n = (ct0 + ct) * 16 + c;
            short8 bf3 = *(const short8*)&w3t[n * 128 + kk * 32 + quad * 8];
            short8 bf4 = *(const short8*)&w4t[n * 128 + kk * 32 + quad * 8];
            acc1[0][ct] = __builtin_amdgcn_mfma_f32_16x16x32_bf16(a0, bf3, acc1[0][ct], 0, 0, 0);
            acc1[1][ct] = __builtin_amdgcn_mfma_f32_16x16x32_bf16(a1, bf3, acc1[1][ct], 0, 0, 0);
            acc2[0][ct] = __builtin_amdgcn_mfma_f32_16x16x32_bf16(a0, bf4, acc2[0][ct], 0, 0, 0);
            acc2[1][ct] = __builtin_amdgcn_mfma_f32_16x16x32_bf16(a1, bf4, acc2[1][ct], 0, 0, 0);
        }
    }

    float dpar[2][4];
#pragma unroll
    for (int rt = 0; rt < 2; rt++)
#pragma unroll
        for (int r = 0; r < 4; r++) dpar[rt][r] = 0.f;

#pragma unroll
    for (int rt = 0; rt < 2; rt++) {
#pragma unroll
        for (int ct = 0; ct < 2; ct++) {
            const int gcol = (ct0 + ct) * 16 + c;
            const float bb3 = b3[gcol], bb4 = b4[gcol];
            ushort w2p[4];
#pragma unroll
            for (int r = 0; r < 4; r++) {
                const float v1 = lrelu(acc1[rt][ct][r] + bb3);
                const float v2 = lrelu(acc2[rt][ct][r] + bb4);
                const int grow = row0 + rt * 16 + quad * 4 + r;
                w1b[(size_t)grow * FF + gcol] = f2bf(v1);
                w2p[r] = f2bf(v2);
                dpar[rt][r] += v1 * v2;
            }
            const uint lo = (uint)w2p[0] | ((uint)w2p[1] << 16);
            const uint hi = (uint)w2p[2] | ((uint)w2p[3] << 16);
            uint2* dst = (uint2*)&w2t[(size_t)b * (FF * NN) + (size_t)gcol * NN +
                                      jloc0 + rt * 16 + quad * 4];
            *dst = make_uint2(lo, hi);
        }
    }

    // diag: reduce dpar across the 16 lanes of each quad-row group
#pragma unroll
    for (int rt = 0; rt < 2; rt++) {
#pragma unroll
        for (int r = 0; r < 4; r++) {
            float dp = dpar[rt][r];
            dp += __shfl_xor(dp, 1, 64);
            dp += __shfl_xor(dp, 2, 64);
            dp += __shfl_xor(dp, 4, 64);
            dp += __shfl_xor(dp, 8, 64);
            if (c == 0) atomicAdd(&diag_s[rt * 16 + quad * 4 + r], dp);
        }
    }
    __syncthreads();
    if (tid < 32) diag[row0 + tid] = diag_s[tid];
}

// ---------------------------------------------------------------------------
// K2: Spart[b][kc][g][f] = sum_{j in chunk kc} xt[b][g][j] * w2t[b][f][j]
// 64 blocks, no LDS. Each wave: 2 g-tiles x 8 f-tiles.
// ---------------------------------------------------------------------------
__global__ __launch_bounds__(256) void k_S(
    const ushort* __restrict__ xt, const ushort* __restrict__ w2t,
    float* __restrict__ Spart)
{
    const int b = blockIdx.x >> 3;
    const int kc = blockIdx.x & 7;
    const int j0 = kc * 256;
    const int tid = threadIdx.x;
    const int lane = tid & 63;
    const int wave = tid >> 6;
    const int c = lane & 15;
    const int quad = lane >> 4;
    const int gt0 = wave * 2;

    const ushort* xtb = xt + (size_t)b * (FF * NN);
    const ushort* w2b = w2t + (size_t)b * (FF * NN);

    f32x4 acc[2][8];
#pragma unroll
    for (int rt = 0; rt < 2; rt++)
#pragma unroll
        for (int ct = 0; ct < 8; ct++) acc[rt][ct] = (f32x4)0.f;

#pragma unroll 2
    for (int it = 0; it < 8; it++) {
        const int jb = j0 + it * 32 + quad * 8;
        short8 a0 = *(const short8*)&xtb[((gt0 + 0) * 16 + c) * NN + jb];
        short8 a1 = *(const short8*)&xtb[((gt0 + 1) * 16 + c) * NN + jb];
#pragma unroll
        for (int ct = 0; ct < 8; ct++) {
            short8 bf = *(const short8*)&w2b[(ct * 16 + c) * NN + jb];
            acc[0][ct] = __builtin_amdgcn_mfma_f32_16x16x32_bf16(a0, bf, acc[0][ct], 0, 0, 0);
            acc[1][ct] = __builtin_amdgcn_mfma_f32_16x16x32_bf16(a1, bf, acc[1][ct], 0, 0, 0);
        }
    }

    float* outp = Spart + ((size_t)(b * 8 + kc)) * (FF * FF);
#pragma unroll
    for (int rt = 0; rt < 2; rt++)
#pragma unroll
        for (int ct = 0; ct < 8; ct++)
#pragma unroll
            for (int r = 0; r < 4; r++) {
                const int g = (gt0 + rt) * 16 + quad * 4 + r;
                const int f = ct * 16 + c;
                outp[g * FF + f] = acc[rt][ct][r];
            }
}

// ---------------------------------------------------------------------------
// K2b: St[b][g][f] = bf16( sum_kc Spart[b][kc][g][f] )
// ---------------------------------------------------------------------------
__global__ __launch_bounds__(256) void k_Sred(
    const float* __restrict__ Spart, ushort* __restrict__ St)
{
    const int idx = blockIdx.x * 256 + threadIdx.x;   // 0 .. 131071
    const int b = idx >> 14;
    const int rem = idx & 16383;
    const float* p = Spart + (size_t)b * (8 * FF * FF) + rem;
    float s = 0.f;
#pragma unroll
    for (int kc = 0; kc < 8; kc++) s += p[kc * FF * FF];
    St[idx] = f2bf(s);
}

// ---------------------------------------------------------------------------
// K3: msg = (w1 @ S - diag*x)/(N-1);  out = lrelu(msg @ W5 + b5) + x
// 32 rows / block, two chained MFMA stages with bf16 msg via LDS.
// ---------------------------------------------------------------------------
__global__ __launch_bounds__(256) void k_out(
    const float* __restrict__ x, const ushort* __restrict__ w1b,
    const ushort* __restrict__ St, const float* __restrict__ diag,
    const ushort* __restrict__ w5t, const float* __restrict__ b5,
    float* __restrict__ out)
{
    __shared__ ushort w1s[32 * XS_STRIDE];
    __shared__ ushort ms[32 * XS_STRIDE];

    const int tid = threadIdx.x;
    const int row0 = blockIdx.x * 32;
    const int b = row0 >> 11;
    const ushort* Sb = St + (size_t)b * (FF * FF);

    // stage w1 tile (bf16) into LDS
#pragma unroll
    for (int i = 0; i < 2; i++) {
        const int e8 = i * 256 + tid;       // short8 index, 512 total
        const int off = e8 * 8;
        const int row = off >> 7;
        const int k = off & 127;
        short8 v = *(const short8*)&w1b[(size_t)row0 * FF + off];
        *(short8*)&w1s[row * XS_STRIDE + k] = v;
    }
    __syncthreads();

    const int lane = tid & 63;
    const int wave = tid >> 6;
    const int c = lane & 15;
    const int quad = lane >> 4;
    const int ct0 = wave * 2;

    f32x4 accm[2][2];
#pragma unroll
    for (int rt = 0; rt < 2; rt++)
#pragma unroll
        for (int ct = 0; ct < 2; ct++) accm[rt][ct] = (f32x4)0.f;

#pragma unroll
    for (int kk = 0; kk < 4; kk++) {
        short8 a0 = *(const short8*)&w1s[c * XS_STRIDE + kk * 32 + quad * 8];
        short8 a1 = *(const short8*)&w1s[(16 + c) * XS_STRIDE + kk * 32 + quad * 8];
#pragma unroll
        for (int ct = 0; ct < 2; ct++) {
            const int n = (ct0 + ct) * 16 + c;
            short8 bf = *(const short8*)&Sb[n * 128 + kk * 32 + quad * 8];
            accm[0][ct] = __builtin_amdgcn_mfma_f32_16x16x32_bf16(a0, bf, accm[0][ct], 0, 0, 0);
            accm[1][ct] = __builtin_amdgcn_mfma_f32_16x16x32_bf16(a1, bf, accm[1][ct], 0, 0, 0);
        }
    }

    // epilogue 1: msg = (acc - diag*x) * inv -> bf16 LDS
    const float inv = 1.f / (float)(NN - 1);
    float xsv[2][2][4];
#pragma unroll
    for (int rt = 0; rt < 2; rt++) {
        float dg[4];
#pragma unroll
        for (int r = 0; r < 4; r++) dg[r] = diag[row0 + rt * 16 + quad * 4 + r];
#pragma unroll
        for (int ct = 0; ct < 2; ct++) {
            const int gcol = (ct0 + ct) * 16 + c;
#pragma unroll
            for (int r = 0; r < 4; r++) {
                const int lrow = rt * 16 + quad * 4 + r;
                const float xv = x[(size_t)(row0 + lrow) * FF + gcol];
                xsv[rt][ct][r] = xv;
                const float m = (accm[rt][ct][r] - dg[r] * xv) * inv;
                ms[lrow * XS_STRIDE + gcol] = f2bf(m);
            }
        }
    }
    __syncthreads();

    f32x4 acc2[2][2];
#pragma unroll
    for (int rt = 0; rt < 2; rt++)
#pragma unroll
        for (int ct = 0; ct < 2; ct++) acc2[rt][ct] = (f32x4)0.f;

#pragma unroll
    for (int kk = 0; kk < 4; kk++) {
        short8 a0 = *(const short8*)&ms[c * XS_STRIDE + kk * 32 + quad * 8];
        short8 a1 = *(const short8*)&ms[(16 + c) * XS_STRIDE + kk * 32 + quad * 8];
#pragma unroll
        for (int ct = 0; ct < 2; ct++) {
            const int n = (ct0 + ct) * 16 + c;
            short8 bf = *(const short8*)&w5t[n * 128 + kk * 32 + quad * 8];
            acc2[0][ct] = __builtin_amdgcn_mfma_f32_16x16x32_bf16(a0, bf, acc2[0][ct], 0, 0, 0);
            acc2[1][ct] = __builtin_amdgcn_mfma_f32_16x16x32_bf16(a1, bf, acc2[1][ct], 0, 0, 0);
        }
    }

    // epilogue 2: out = lrelu(acc2 + b5) + x
#pragma unroll
    for (int rt = 0; rt < 2; rt++) {
#pragma unroll
        for (int ct = 0; ct < 2; ct++) {
            const int gcol = (ct0 + ct) * 16 + c;
            const float bb = b5[gcol];
#pragma unroll
            for (int r = 0; r < 4; r++) {
                const int grow = row0 + rt * 16 + quad * 4 + r;
                out[(size_t)grow * FF + gcol] = lrelu(acc2[rt][ct][r] + bb) + xsv[rt][ct][r];
            }
        }
    }
}

// ---------------------------------------------------------------------------
extern "C" void kernel_launch(void* const* d_in, const int* in_sizes, int n_in,
                              void* d_out, int out_size, void* d_ws, size_t ws_size,
                              hipStream_t stream)
{
    const float* x  = (const float*)d_in[0];
    const float* W3 = (const float*)d_in[1];
    const float* b3 = (const float*)d_in[2];
    const float* W4 = (const float*)d_in[3];
    const float* b4 = (const float*)d_in[4];
    const float* W5 = (const float*)d_in[5];
    const float* b5 = (const float*)d_in[6];
    float* out = (float*)d_out;

    char* ws = (char*)d_ws;
    ushort* w1b   = (ushort*)(ws);                       // 4 MB bf16 [16384][128]
    ushort* w2t   = (ushort*)(ws + ((size_t)4  << 20));  // 4 MB bf16 [8][128][2048]
    ushort* xt    = (ushort*)(ws + ((size_t)8  << 20));  // 4 MB bf16 [8][128][2048]
    float*  diag  = (float*) (ws + ((size_t)12 << 20));  // 64 KB fp32 [16384]
    float*  Spart = (float*) (ws + ((size_t)13 << 20));  // 4 MB fp32 [8][8][128][128]
    ushort* St    = (ushort*)(ws + ((size_t)17 << 20));  // 256 KB bf16 [8][128][128]
    ushort* Wt    = (ushort*)(ws + ((size_t)18 << 20));  // 192 KB bf16 [6][128][128]

    k_prep<<<384, 256, 0, stream>>>(W3, W4, W5, Wt);

    const int rowBlocks = NROW / 32;   // 512

    for (int l = 0; l < NL; l++) {
        const float* cur = (l == 0) ? x : out;
        const ushort* w3tl = Wt + (size_t)(l * 3 + 0) * 16384;
        const ushort* w4tl = Wt + (size_t)(l * 3 + 1) * 16384;
        const ushort* w5tl = Wt + (size_t)(l * 3 + 2) * 16384;
        const float* b3l = b3 + (size_t)l * FF;
        const float* b4l = b4 + (size_t)l * FF;
        const float* b5l = b5 + (size_t)l * FF;

        k_w12<<<rowBlocks, 256, 0, stream>>>(cur, w3tl, w4tl, b3l, b4l,
                                             w1b, w2t, xt, diag);
        k_S<<<64, 256, 0, stream>>>(xt, w2t, Spart);
        k_Sred<<<512, 256, 0, stream>>>(Spart, St);
        k_out<<<rowBlocks, 256, 0, stream>>>(cur, w1b, St, diag, w5tl, b5l, out);
    }
}

// Round 3
// 122.869 us; speedup vs baseline: 1.9620x; 1.2248x over previous
//
#include <hip/hip_runtime.h>

#define BB 8
#define NN 2048
#define FF 128
#define NL 2
#define SLOPE 0.1f
#define NROW (BB * NN)          // 16384 total rows
#define XS_STRIDE 136           // padded bf16 row stride in LDS

typedef __attribute__((ext_vector_type(8))) short short8;
typedef __attribute__((ext_vector_type(4))) float f32x4;

__device__ __forceinline__ float lrelu(float v) { return v >= 0.f ? v : SLOPE * v; }

// fp32 -> bf16 round-to-nearest-even
__device__ __forceinline__ ushort f2bf(float f) {
    uint u = __float_as_uint(f);
    return (ushort)((u + 0x7fffu + ((u >> 16) & 1u)) >> 16);
}

// ---------------------------------------------------------------------------
// Prep: transpose all 6 weight matrices to bf16 Wt[m][g][f] = W[m][f][g]
// m = l*3 + {0:W3, 1:W4, 2:W5}
// ---------------------------------------------------------------------------
__global__ __launch_bounds__(256) void k_prep(
    const float* __restrict__ W3, const float* __restrict__ W4,
    const float* __restrict__ W5, ushort* __restrict__ Wt)
{
    const int idx = blockIdx.x * 256 + threadIdx.x;   // 0 .. 98303
    const int m = idx >> 14;
    const int rem = idx & 16383;
    const int f = rem & 127;
    const int g = rem >> 7;
    const int l = m / 3, w = m % 3;
    const float* src = (w == 0) ? W3 : (w == 1) ? W4 : W5;
    Wt[m * 16384 + g * 128 + f] = f2bf(src[l * 16384 + f * 128 + g]);
}

// ---------------------------------------------------------------------------
// K1: w1 = lrelu(x@W3+b3) [bf16 row-major], w2t[b][f][j] = lrelu(x@W4+b4)^T,
//     xt[b][g][j] = x^T (bf16), diag[i] = dot(w1_i, w2_i).  32 rows / block.
// ---------------------------------------------------------------------------
__global__ __launch_bounds__(256) void k_w12(
    const float* __restrict__ x, const ushort* __restrict__ w3t,
    const ushort* __restrict__ w4t, const float* __restrict__ b3,
    const float* __restrict__ b4, ushort* __restrict__ w1b,
    ushort* __restrict__ w2t, ushort* __restrict__ xt,
    float* __restrict__ diag)
{
    __shared__ ushort xs[32 * XS_STRIDE];
    __shared__ float diag_s[32];

    const int tid = threadIdx.x;
    const int row0 = blockIdx.x * 32;
    const int b = row0 >> 11;          // batch
    const int jloc0 = row0 & 2047;     // row within batch

    if (tid < 32) diag_s[tid] = 0.f;

    // stage x tile -> bf16 LDS (row-major, padded)
    const float4* xg4 = (const float4*)(x + (size_t)row0 * FF);
#pragma unroll
    for (int i = 0; i < 4; i++) {
        const int f4 = i * 256 + tid;          // float4 index in tile
        const int row = f4 >> 5;
        const int k = (f4 & 31) * 4;
        float4 v = xg4[f4];
        ushort4 h;
        h.x = f2bf(v.x); h.y = f2bf(v.y); h.z = f2bf(v.z); h.w = f2bf(v.w);
        *(ushort4*)&xs[row * XS_STRIDE + k] = h;
    }
    __syncthreads();

    // write xt[b][g][jloc0..+32] from LDS (transposed read)
    {
        const int g = tid >> 1;
        const int h = tid & 1;
        uint p[8];
#pragma unroll
        for (int jj = 0; jj < 8; jj++) {
            const uint lo = xs[(h * 16 + jj * 2) * XS_STRIDE + g];
            const uint hi = xs[(h * 16 + jj * 2 + 1) * XS_STRIDE + g];
            p[jj] = lo | (hi << 16);
        }
        uint4* dst = (uint4*)&xt[(size_t)b * (FF * NN) + (size_t)g * NN + jloc0 + h * 16];
        dst[0] = make_uint4(p[0], p[1], p[2], p[3]);
        dst[1] = make_uint4(p[4], p[5], p[6], p[7]);
    }

    const int lane = tid & 63;
    const int wave = tid >> 6;
    const int c = lane & 15;
    const int quad = lane >> 4;
    const int ct0 = wave * 2;

    f32x4 acc1[2][2], acc2[2][2];
#pragma unroll
    for (int rt = 0; rt < 2; rt++)
#pragma unroll
        for (int ct = 0; ct < 2; ct++) { acc1[rt][ct] = (f32x4)0.f; acc2[rt][ct] = (f32x4)0.f; }

#pragma unroll
    for (int kk = 0; kk < 4; kk++) {
        short8 a0 = *(const short8*)&xs[c * XS_STRIDE + kk * 32 + quad * 8];
        short8 a1 = *(const short8*)&xs[(16 + c) * XS_STRIDE + kk * 32 + quad * 8];
#pragma unroll
        for (int ct = 0; ct < 2; ct++) {
            const int n = (ct0 + ct) * 16 + c;
            short8 bf3 = *(const short8*)&w3t[n * 128 + kk * 32 + quad * 8];
            short8 bf4 = *(const short8*)&w4t[n * 128 + kk * 32 + quad * 8];
            acc1[0][ct] = __builtin_amdgcn_mfma_f32_16x16x32_bf16(a0, bf3, acc1[0][ct], 0, 0, 0);
            acc1[1][ct] = __builtin_amdgcn_mfma_f32_16x16x32_bf16(a1, bf3, acc1[1][ct], 0, 0, 0);
            acc2[0][ct] = __builtin_amdgcn_mfma_f32_16x16x32_bf16(a0, bf4, acc2[0][ct], 0, 0, 0);
            acc2[1][ct] = __builtin_amdgcn_mfma_f32_16x16x32_bf16(a1, bf4, acc2[1][ct], 0, 0, 0);
        }
    }

    float dpar[2][4];
#pragma unroll
    for (int rt = 0; rt < 2; rt++)
#pragma unroll
        for (int r = 0; r < 4; r++) dpar[rt][r] = 0.f;

#pragma unroll
    for (int rt = 0; rt < 2; rt++) {
#pragma unroll
        for (int ct = 0; ct < 2; ct++) {
            const int gcol = (ct0 + ct) * 16 + c;
            const float bb3 = b3[gcol], bb4 = b4[gcol];
            ushort w2p[4];
#pragma unroll
            for (int r = 0; r < 4; r++) {
                const float v1 = lrelu(acc1[rt][ct][r] + bb3);
                const float v2 = lrelu(acc2[rt][ct][r] + bb4);
                const int grow = row0 + rt * 16 + quad * 4 + r;
                w1b[(size_t)grow * FF + gcol] = f2bf(v1);
                w2p[r] = f2bf(v2);
                dpar[rt][r] += v1 * v2;
            }
            const uint lo = (uint)w2p[0] | ((uint)w2p[1] << 16);
            const uint hi = (uint)w2p[2] | ((uint)w2p[3] << 16);
            uint2* dst = (uint2*)&w2t[(size_t)b * (FF * NN) + (size_t)gcol * NN +
                                      jloc0 + rt * 16 + quad * 4];
            *dst = make_uint2(lo, hi);
        }
    }

    // diag: reduce dpar across the 16 lanes of each quad-row group
#pragma unroll
    for (int rt = 0; rt < 2; rt++) {
#pragma unroll
        for (int r = 0; r < 4; r++) {
            float dp = dpar[rt][r];
            dp += __shfl_xor(dp, 1, 64);
            dp += __shfl_xor(dp, 2, 64);
            dp += __shfl_xor(dp, 4, 64);
            dp += __shfl_xor(dp, 8, 64);
            if (c == 0) atomicAdd(&diag_s[rt * 16 + quad * 4 + r], dp);
        }
    }
    __syncthreads();
    if (tid < 32) diag[row0 + tid] = diag_s[tid];
}

// ---------------------------------------------------------------------------
// K2: St[b][g][f] = bf16( sum_j xt[b][g][j] * w2t[b][f][j] )
// grid = 8 batch x 4 g-quarters x 8 f-strips = 256 blocks.
// Waves split K (512 each); LDS reduce; write bf16 directly.
// ---------------------------------------------------------------------------
__global__ __launch_bounds__(256) void k_S2(
    const ushort* __restrict__ xt, const ushort* __restrict__ w2t,
    ushort* __restrict__ St)
{
    __shared__ float red[4][512];   // 8 KB
    const int tid = threadIdx.x;
    const int lane = tid & 63;
    const int wave = tid >> 6;
    const int c = lane & 15;
    const int quad = lane >> 4;

    const int b  = blockIdx.x >> 5;         // 0..7
    const int gq = (blockIdx.x >> 3) & 3;   // g-quarter (32 g)
    const int fs = blockIdx.x & 7;          // f-strip (16 f)

    const ushort* xtb = xt + (size_t)b * (FF * NN);
    const ushort* w2b = w2t + (size_t)b * (FF * NN);

    const int j0 = wave * 512 + quad * 8;
    const ushort* a0p = &xtb[(gq * 32 + c) * NN + j0];
    const ushort* a1p = &xtb[(gq * 32 + 16 + c) * NN + j0];
    const ushort* bp  = &w2b[(fs * 16 + c) * NN + j0];

    f32x4 acc0 = (f32x4)0.f, acc1 = (f32x4)0.f;
#pragma unroll
    for (int it = 0; it < 16; it++) {
        short8 a0 = *(const short8*)(a0p + it * 32);
        short8 a1 = *(const short8*)(a1p + it * 32);
        short8 bf = *(const short8*)(bp + it * 32);
        acc0 = __builtin_amdgcn_mfma_f32_16x16x32_bf16(a0, bf, acc0, 0, 0, 0);
        acc1 = __builtin_amdgcn_mfma_f32_16x16x32_bf16(a1, bf, acc1, 0, 0, 0);
    }

#pragma unroll
    for (int r = 0; r < 4; r++) {
        red[wave][(quad * 4 + r) * 16 + c] = acc0[r];
        red[wave][(16 + quad * 4 + r) * 16 + c] = acc1[r];
    }
    __syncthreads();

#pragma unroll
    for (int i = 0; i < 2; i++) {
        const int idx = i * 256 + tid;
        const float s = red[0][idx] + red[1][idx] + red[2][idx] + red[3][idx];
        const int gl = idx >> 4;
        const int fl = idx & 15;
        St[(size_t)b * (FF * FF) + (size_t)(gq * 32 + gl) * FF + fs * 16 + fl] = f2bf(s);
    }
}

// ---------------------------------------------------------------------------
// K3: msg = (w1 @ S - diag*x)/(N-1);  out = lrelu(msg @ W5 + b5) + x
// ---------------------------------------------------------------------------
__global__ __launch_bounds__(256) void k_out(
    const float* __restrict__ x, const ushort* __restrict__ w1b,
    const ushort* __restrict__ St, const float* __restrict__ diag,
    const ushort* __restrict__ w5t, const float* __restrict__ b5,
    float* __restrict__ out)
{
    __shared__ ushort w1s[32 * XS_STRIDE];
    __shared__ ushort ms[32 * XS_STRIDE];

    const int tid = threadIdx.x;
    const int row0 = blockIdx.x * 32;
    const int b = row0 >> 11;
    const ushort* Sb = St + (size_t)b * (FF * FF);

#pragma unroll
    for (int i = 0; i < 2; i++) {
        const int e8 = i * 256 + tid;
        const int off = e8 * 8;
        const int row = off >> 7;
        const int k = off & 127;
        short8 v = *(const short8*)&w1b[(size_t)row0 * FF + off];
        *(short8*)&w1s[row * XS_STRIDE + k] = v;
    }
    __syncthreads();

    const int lane = tid & 63;
    const int wave = tid >> 6;
    const int c = lane & 15;
    const int quad = lane >> 4;
    const int ct0 = wave * 2;

    f32x4 accm[2][2];
#pragma unroll
    for (int rt = 0; rt < 2; rt++)
#pragma unroll
        for (int ct = 0; ct < 2; ct++) accm[rt][ct] = (f32x4)0.f;

#pragma unroll
    for (int kk = 0; kk < 4; kk++) {
        short8 a0 = *(const short8*)&w1s[c * XS_STRIDE + kk * 32 + quad * 8];
        short8 a1 = *(const short8*)&w1s[(16 + c) * XS_STRIDE + kk * 32 + quad * 8];
#pragma unroll
        for (int ct = 0; ct < 2; ct++) {
            const int n = (ct0 + ct) * 16 + c;
            short8 bf = *(const short8*)&Sb[n * 128 + kk * 32 + quad * 8];
            accm[0][ct] = __builtin_amdgcn_mfma_f32_16x16x32_bf16(a0, bf, accm[0][ct], 0, 0, 0);
            accm[1][ct] = __builtin_amdgcn_mfma_f32_16x16x32_bf16(a1, bf, accm[1][ct], 0, 0, 0);
        }
    }

    const float inv = 1.f / (float)(NN - 1);
    float xsv[2][2][4];
#pragma unroll
    for (int rt = 0; rt < 2; rt++) {
        float dg[4];
#pragma unroll
        for (int r = 0; r < 4; r++) dg[r] = diag[row0 + rt * 16 + quad * 4 + r];
#pragma unroll
        for (int ct = 0; ct < 2; ct++) {
            const int gcol = (ct0 + ct) * 16 + c;
#pragma unroll
            for (int r = 0; r < 4; r++) {
                const int lrow = rt * 16 + quad * 4 + r;
                const float xv = x[(size_t)(row0 + lrow) * FF + gcol];
                xsv[rt][ct][r] = xv;
                const float m = (accm[rt][ct][r] - dg[r] * xv) * inv;
                ms[lrow * XS_STRIDE + gcol] = f2bf(m);
            }
        }
    }
    __syncthreads();

    f32x4 acc2[2][2];
#pragma unroll
    for (int rt = 0; rt < 2; rt++)
#pragma unroll
        for (int ct = 0; ct < 2; ct++) acc2[rt][ct] = (f32x4)0.f;

#pragma unroll
    for (int kk = 0; kk < 4; kk++) {
        short8 a0 = *(const short8*)&ms[c * XS_STRIDE + kk * 32 + quad * 8];
        short8 a1 = *(const short8*)&ms[(16 + c) * XS_STRIDE + kk * 32 + quad * 8];
#pragma unroll
        for (int ct = 0; ct < 2; ct++) {
            const int n = (ct0 + ct) * 16 + c;
            short8 bf = *(const short8*)&w5t[n * 128 + kk * 32 + quad * 8];
            acc2[0][ct] = __builtin_amdgcn_mfma_f32_16x16x32_bf16(a0, bf, acc2[0][ct], 0, 0, 0);
            acc2[1][ct] = __builtin_amdgcn_mfma_f32_16x16x32_bf16(a1, bf, acc2[1][ct], 0, 0, 0);
        }
    }

#pragma unroll
    for (int rt = 0; rt < 2; rt++) {
#pragma unroll
        for (int ct = 0; ct < 2; ct++) {
            const int gcol = (ct0 + ct) * 16 + c;
            const float bb = b5[gcol];
#pragma unroll
            for (int r = 0; r < 4; r++) {
                const int grow = row0 + rt * 16 + quad * 4 + r;
                out[(size_t)grow * FF + gcol] = lrelu(acc2[rt][ct][r] + bb) + xsv[rt][ct][r];
            }
        }
    }
}

// ---------------------------------------------------------------------------
// K4: fused k_out(layer l) + k_w12(layer l+1).
// Phase A = k_out, keeping the output tile in registers; Phase B re-uses the
// bf16 output tile in LDS to run next layer's w1/w2/xt/diag without reloading.
// Aliasing note: each block touches only its own 32 rows of w1b/diag, so
// reading layer-l values and writing layer-(l+1) values in place is safe.
// ---------------------------------------------------------------------------
__global__ __launch_bounds__(256) void k_out_w12(
    const float* __restrict__ x, const ushort* __restrict__ w1b_in,
    const ushort* __restrict__ St, const float* __restrict__ diag_in,
    const ushort* __restrict__ w5t, const float* __restrict__ b5,
    float* __restrict__ out,
    const ushort* __restrict__ w3t, const ushort* __restrict__ w4t,
    const float* __restrict__ b3, const float* __restrict__ b4,
    ushort* __restrict__ w1b, ushort* __restrict__ w2t,
    ushort* __restrict__ xt, float* __restrict__ diag)
{
    __shared__ ushort sA[32 * XS_STRIDE];   // w1 tile, then out tile (bf16)
    __shared__ ushort sB[32 * XS_STRIDE];   // msg tile
    __shared__ float diag_s[32];

    const int tid = threadIdx.x;
    const int row0 = blockIdx.x * 32;
    const int b = row0 >> 11;
    const int jloc0 = row0 & 2047;
    const ushort* Sb = St + (size_t)b * (FF * FF);

    if (tid < 32) diag_s[tid] = 0.f;

    // ---- Phase A: out = lrelu((w1@S - diag*x)/(N-1) @ W5 + b5) + x ----
#pragma unroll
    for (int i = 0; i < 2; i++) {
        const int e8 = i * 256 + tid;
        const int off = e8 * 8;
        const int row = off >> 7;
        const int k = off & 127;
        short8 v = *(const short8*)&w1b_in[(size_t)row0 * FF + off];
        *(short8*)&sA[row * XS_STRIDE + k] = v;
    }
    __syncthreads();

    const int lane = tid & 63;
    const int wave = tid >> 6;
    const int c = lane & 15;
    const int quad = lane >> 4;
    const int ct0 = wave * 2;

    f32x4 accm[2][2];
#pragma unroll
    for (int rt = 0; rt < 2; rt++)
#pragma unroll
        for (int ct = 0; ct < 2; ct++) accm[rt][ct] = (f32x4)0.f;

#pragma unroll
    for (int kk = 0; kk < 4; kk++) {
        short8 a0 = *(const short8*)&sA[c * XS_STRIDE + kk * 32 + quad * 8];
        short8 a1 = *(const short8*)&sA[(16 + c) * XS_STRIDE + kk * 32 + quad * 8];
#pragma unroll
        for (int ct = 0; ct < 2; ct++) {
            const int n = (ct0 + ct) * 16 + c;
            short8 bf = *(const short8*)&Sb[n * 128 + kk * 32 + quad * 8];
            accm[0][ct] = __builtin_amdgcn_mfma_f32_16x16x32_bf16(a0, bf, accm[0][ct], 0, 0, 0);
            accm[1][ct] = __builtin_amdgcn_mfma_f32_16x16x32_bf16(a1, bf, accm[1][ct], 0, 0, 0);
        }
    }

    const float inv = 1.f / (float)(NN - 1);
    float xsv[2][2][4];
#pragma unroll
    for (int rt = 0; rt < 2; rt++) {
        float dg[4];
#pragma unroll
        for (int r = 0; r < 4; r++) dg[r] = diag_in[row0 + rt * 16 + quad * 4 + r];
#pragma unroll
        for (int ct = 0; ct < 2; ct++) {
            const int gcol = (ct0 + ct) * 16 + c;
#pragma unroll
            for (int r = 0; r < 4; r++) {
                const int lrow = rt * 16 + quad * 4 + r;
                const float xv = x[(size_t)(row0 + lrow) * FF + gcol];
                xsv[rt][ct][r] = xv;
                const float m = (accm[rt][ct][r] - dg[r] * xv) * inv;
                sB[lrow * XS_STRIDE + gcol] = f2bf(m);
            }
        }
    }
    __syncthreads();   // sB ready; sA (w1 tile) now dead

    f32x4 acc2[2][2];
#pragma unroll
    for (int rt = 0; rt < 2; rt++)
#pragma unroll
        for (int ct = 0; ct < 2; ct++) acc2[rt][ct] = (f32x4)0.f;

#pragma unroll
    for (int kk = 0; kk < 4; kk++) {
        short8 a0 = *(const short8*)&sB[c * XS_STRIDE + kk * 32 + quad * 8];
        short8 a1 = *(const short8*)&sB[(16 + c) * XS_STRIDE + kk * 32 + quad * 8];
#pragma unroll
        for (int ct = 0; ct < 2; ct++) {
            const int n = (ct0 + ct) * 16 + c;
            short8 bf = *(const short8*)&w5t[n * 128 + kk * 32 + quad * 8];
            acc2[0][ct] = __builtin_amdgcn_mfma_f32_16x16x32_bf16(a0, bf, acc2[0][ct], 0, 0, 0);
            acc2[1][ct] = __builtin_amdgcn_mfma_f32_16x16x32_bf16(a1, bf, acc2[1][ct], 0, 0, 0);
        }
    }

    // epilogue: write out (fp32 global) + stash bf16 out tile in sA
#pragma unroll
    for (int rt = 0; rt < 2; rt++) {
#pragma unroll
        for (int ct = 0; ct < 2; ct++) {
            const int gcol = (ct0 + ct) * 16 + c;
            const float bb = b5[gcol];
#pragma unroll
            for (int r = 0; r < 4; r++) {
                const int lrow = rt * 16 + quad * 4 + r;
                const float ov = lrelu(acc2[rt][ct][r] + bb) + xsv[rt][ct][r];
                out[(size_t)(row0 + lrow) * FF + gcol] = ov;
                sA[lrow * XS_STRIDE + gcol] = f2bf(ov);
            }
        }
    }
    __syncthreads();   // sA = bf16 out tile, visible to all waves

    // ---- Phase B: next layer's w1/w2/xt/diag from sA ----
    {
        const int g = tid >> 1;
        const int h = tid & 1;
        uint p[8];
#pragma unroll
        for (int jj = 0; jj < 8; jj++) {
            const uint lo = sA[(h * 16 + jj * 2) * XS_STRIDE + g];
            const uint hi = sA[(h * 16 + jj * 2 + 1) * XS_STRIDE + g];
            p[jj] = lo | (hi << 16);
        }
        uint4* dst = (uint4*)&xt[(size_t)b * (FF * NN) + (size_t)g * NN + jloc0 + h * 16];
        dst[0] = make_uint4(p[0], p[1], p[2], p[3]);
        dst[1] = make_uint4(p[4], p[5], p[6], p[7]);
    }

    f32x4 acc1n[2][2], acc2n[2][2];
#pragma unroll
    for (int rt = 0; rt < 2; rt++)
#pragma unroll
        for (int ct = 0; ct < 2; ct++) { acc1n[rt][ct] = (f32x4)0.f; acc2n[rt][ct] = (f32x4)0.f; }

#pragma unroll
    for (int kk = 0; kk < 4; kk++) {
        short8 a0 = *(const short8*)&sA[c * XS_STRIDE + kk * 32 + quad * 8];
        short8 a1 = *(const short8*)&sA[(16 + c) * XS_STRIDE + kk * 32 + quad * 8];
#pragma unroll
        for (int ct = 0; ct < 2; ct++) {
            const int n = (ct0 + ct) * 16 + c;
            short8 bf3 = *(const short8*)&w3t[n * 128 + kk * 32 + quad * 8];
            short8 bf4 = *(const short8*)&w4t[n * 128 + kk * 32 + quad * 8];
            acc1n[0][ct] = __builtin_amdgcn_mfma_f32_16x16x32_bf16(a0, bf3, acc1n[0][ct], 0, 0, 0);
            acc1n[1][ct] = __builtin_amdgcn_mfma_f32_16x16x32_bf16(a1, bf3, acc1n[1][ct], 0, 0, 0);
            acc2n[0][ct] = __builtin_amdgcn_mfma_f32_16x16x32_bf16(a0, bf4, acc2n[0][ct], 0, 0, 0);
            acc2n[1][ct] = __builtin_amdgcn_mfma_f32_16x16x32_bf16(a1, bf4, acc2n[1][ct], 0, 0, 0);
        }
    }

    float dpar[2][4];
#pragma unroll
    for (int rt = 0; rt < 2; rt++)
#pragma unroll
        for (int r = 0; r < 4; r++) dpar[rt][r] = 0.f;

#pragma unroll
    for (int rt = 0; rt < 2; rt++) {
#pragma unroll
        for (int ct = 0; ct < 2; ct++) {
            const int gcol = (ct0 + ct) * 16 + c;
            const float bb3 = b3[gcol], bb4 = b4[gcol];
            ushort w2p[4];
#pragma unroll
            for (int r = 0; r < 4; r++) {
                const float v1 = lrelu(acc1n[rt][ct][r] + bb3);
                const float v2 = lrelu(acc2n[rt][ct][r] + bb4);
                const int grow = row0 + rt * 16 + quad * 4 + r;
                w1b[(size_t)grow * FF + gcol] = f2bf(v1);
                w2p[r] = f2bf(v2);
                dpar[rt][r] += v1 * v2;
            }
            const uint lo = (uint)w2p[0] | ((uint)w2p[1] << 16);
            const uint hi = (uint)w2p[2] | ((uint)w2p[3] << 16);
            uint2* dst = (uint2*)&w2t[(size_t)b * (FF * NN) + (size_t)gcol * NN +
                                      jloc0 + rt * 16 + quad * 4];
            *dst = make_uint2(lo, hi);
        }
    }

#pragma unroll
    for (int rt = 0; rt < 2; rt++) {
#pragma unroll
        for (int r = 0; r < 4; r++) {
            float dp = dpar[rt][r];
            dp += __shfl_xor(dp, 1, 64);
            dp += __shfl_xor(dp, 2, 64);
            dp += __shfl_xor(dp, 4, 64);
            dp += __shfl_xor(dp, 8, 64);
            if (c == 0) atomicAdd(&diag_s[rt * 16 + quad * 4 + r], dp);
        }
    }
    __syncthreads();
    if (tid < 32) diag[row0 + tid] = diag_s[tid];
}

// ---------------------------------------------------------------------------
extern "C" void kernel_launch(void* const* d_in, const int* in_sizes, int n_in,
                              void* d_out, int out_size, void* d_ws, size_t ws_size,
                              hipStream_t stream)
{
    const float* x  = (const float*)d_in[0];
    const float* W3 = (const float*)d_in[1];
    const float* b3 = (const float*)d_in[2];
    const float* W4 = (const float*)d_in[3];
    const float* b4 = (const float*)d_in[4];
    const float* W5 = (const float*)d_in[5];
    const float* b5 = (const float*)d_in[6];
    float* out = (float*)d_out;

    char* ws = (char*)d_ws;
    ushort* w1b   = (ushort*)(ws);                       // 4 MB bf16 [16384][128]
    ushort* w2t   = (ushort*)(ws + ((size_t)4  << 20));  // 4 MB bf16 [8][128][2048]
    ushort* xt    = (ushort*)(ws + ((size_t)8  << 20));  // 4 MB bf16 [8][128][2048]
    float*  diag  = (float*) (ws + ((size_t)12 << 20));  // 64 KB fp32 [16384]
    ushort* St    = (ushort*)(ws + ((size_t)13 << 20));  // 256 KB bf16 [8][128][128]
    ushort* Wt    = (ushort*)(ws + ((size_t)14 << 20));  // 192 KB bf16 [6][128][128]

    const ushort* w3t0 = Wt;
    const ushort* w4t0 = Wt + 16384;
    const ushort* w5t0 = Wt + 2 * 16384;
    const ushort* w3t1 = Wt + 3 * 16384;
    const ushort* w4t1 = Wt + 4 * 16384;
    const ushort* w5t1 = Wt + 5 * 16384;

    const int rowBlocks = NROW / 32;   // 512

    k_prep<<<384, 256, 0, stream>>>(W3, W4, W5, Wt);

    // Layer 0
    k_w12<<<rowBlocks, 256, 0, stream>>>(x, w3t0, w4t0, b3, b4, w1b, w2t, xt, diag);
    k_S2<<<256, 256, 0, stream>>>(xt, w2t, St);
    // Layer 0 output + Layer 1 w12, fused
    k_out_w12<<<rowBlocks, 256, 0, stream>>>(x, w1b, St, diag, w5t0, b5, out,
                                             w3t1, w4t1, b3 + FF, b4 + FF,
                                             w1b, w2t, xt, diag);
    // Layer 1
    k_S2<<<256, 256, 0, stream>>>(xt, w2t, St);
    k_out<<<rowBlocks, 256, 0, stream>>>(out, w1b, St, diag, w5t1, b5 + FF, out);
}